// Round 18
// baseline (1932.983 us; speedup 1.0000x reference)
//
#include <hip/hip_runtime.h>
#include <math.h>

#define BATCH 64
#define LPRE 256
#define EMBD 512
#define HID 1024
#define G3 3072
#define SRC 512
#define VOCAB 32000

typedef unsigned int uint32;
typedef unsigned long long u64;
typedef short bf16x8 __attribute__((ext_vector_type(8)));
typedef float f32x4 __attribute__((ext_vector_type(4)));
typedef uint32 u32x4 __attribute__((ext_vector_type(4)));

__device__ __forceinline__ float frcp_(float x) { return __builtin_amdgcn_rcpf(x); }
__device__ __forceinline__ float sigmoidf_(float x) {
    x = fminf(fmaxf(x, -30.f), 30.f);
    return frcp_(1.0f + __expf(-x));
}
__device__ __forceinline__ float tanhf_(float x) {
    x = fminf(fmaxf(x, -15.f), 15.f);
    float e = __expf(2.f * x);
    return (e - 1.f) * frcp_(e + 1.f);
}

__device__ __forceinline__ unsigned short f2bf(float f) {
    uint32 u = __float_as_uint(f);
    return (unsigned short)((u + 0x7fffu + ((u >> 16) & 1u)) >> 16);
}
__device__ __forceinline__ float bf2f(unsigned short s) { return __uint_as_float(((uint32)s) << 16); }
__device__ __forceinline__ uint4 pack8(float4 a, float4 b) {
    uint4 w;
    w.x = (uint32)f2bf(a.x) | ((uint32)f2bf(a.y) << 16);
    w.y = (uint32)f2bf(a.z) | ((uint32)f2bf(a.w) << 16);
    w.z = (uint32)f2bf(b.x) | ((uint32)f2bf(b.y) << 16);
    w.w = (uint32)f2bf(b.z) | ((uint32)f2bf(b.w) << 16);
    return w;
}
__device__ __forceinline__ void up2(uint32 u, float& f0, float& f1) {
    f0 = __uint_as_float(u << 16);
    f1 = __uint_as_float(u & 0xffff0000u);
}

// -------- fused fp32->bf16 conversion: 10 strided segments, one launch.
struct CvtSeg { const float* src; unsigned short* dst; int ld, off, colshift; uint32 gend; };
struct CvtArgs { CvtSeg s[10]; uint32 total; };

__global__ __launch_bounds__(256) void kcvtN(CvtArgs a) {
    uint32 stride = gridDim.x * 256;
    for (uint32 g = blockIdx.x * 256 + threadIdx.x; g < a.total; g += stride) {
        uint32 gs = 0;
#pragma unroll
        for (int k = 0; k < 10; k++) {
            if (g < a.s[k].gend) {
                uint32 lg = g - gs;
                size_t e = (size_t)lg * 4;
                int r = (int)(e >> a.s[k].colshift);
                int c = (int)(e & (((size_t)1 << a.s[k].colshift) - 1));
                const float* sp = a.s[k].src + (size_t)r * a.s[k].ld + a.s[k].off + c;
                float4 v = *(const float4*)sp;
                uint2 w;
                w.x = (uint32)f2bf(v.x) | ((uint32)f2bf(v.y) << 16);
                w.y = (uint32)f2bf(v.z) | ((uint32)f2bf(v.w) << 16);
                *(uint2*)(a.s[k].dst + e) = w;
                break;
            }
            gs = a.s[k].gend;
        }
    }
}

// -------- persistent GRU recurrence: ALL 256 steps in ONE launch, with the
// input projection fused in (each block computes its own private xw slice for
// step t+1 during step t, in idle barrier shadow; no global xw buffer).
// Grid 256 blocks x 512 thr. Block = (gru, batch-half 32, 16-unit tile).
// Wave = one of 8 disjoint K-slices; h exchange + 4-domain leader+gen barrier
// byte-identical to the proven 1.873ms kernel.
__global__ __launch_bounds__(512, 2) void kstepP(unsigned short* __restrict__ hbp,
                                                 float* __restrict__ hf,
                                                 const unsigned short* __restrict__ Whhb,
                                                 const unsigned short* __restrict__ Wihb,
                                                 const unsigned short* __restrict__ embb,
                                                 const int* __restrict__ pre_seq,
                                                 const int* __restrict__ post_seq,
                                                 const float* __restrict__ bhh0,
                                                 const float* __restrict__ bhh1,
                                                 const float* __restrict__ bih0,
                                                 const float* __restrict__ bih1,
                                                 unsigned short* __restrict__ enc,
                                                 uint32* __restrict__ bar) {
    __shared__ float gl[8][32][3][17];          // 52 KB: K-slice partials (h AND xw phases)
    __shared__ unsigned short hsh[32][16];      // 1 KB
    __shared__ unsigned short xsh[2][32][3][16];// 6 KB: xw double buffer (bf16, bih folded)
    int gru = blockIdx.z;
    int mh = blockIdx.y;
    int u0 = blockIdx.x * 16;
    int tid = threadIdx.x;
    int ks = tid >> 6;                    // 0..7 K-slice
    int lane = tid & 63;
    int q = lane >> 4, m = lane & 15;
    int bbase = mh * 32;
    const unsigned short* Wg = Whhb + (size_t)gru * G3 * HID;
    const unsigned short* Wx = Wihb + (size_t)gru * G3 * EMBD;
    const int* seq = gru ? post_seq : pre_seq;
    const float* bhh = gru ? bhh1 : bhh0;
    const float* bih = gru ? bih1 : bih0;

    int dom = gru * 2 + mh;
    uint32* slots = bar + (size_t)dom * 128;
    uint32* gen = bar + 512 + (size_t)dom * 32;
    int sid = blockIdx.x;
    bool leader = (blockIdx.x == 0);

    // Whh fragments (pinned)
    bf16x8 bfrag[3][4];
#pragma unroll
    for (int g = 0; g < 3; ++g) {
        const unsigned short* pb = Wg + (size_t)(g * HID + u0 + m) * HID + ks * 128 + q * 8;
#pragma unroll
        for (int it = 0; it < 4; ++it) bfrag[g][it] = *(const bf16x8*)(pb + it * 32);
    }
    // Wih fragments for this wave's xw K-slice (64 cols)
    bf16x8 bx[3][2];
#pragma unroll
    for (int g = 0; g < 3; ++g) {
        const unsigned short* pb = Wx + (size_t)(g * HID + u0 + m) * EMBD + ks * 64 + q * 8;
#pragma unroll
        for (int it = 0; it < 2; ++it) bx[g][it] = *(const bf16x8*)(pb + it * 32);
    }
#pragma unroll
    for (int g = 0; g < 3; ++g) {
#pragma unroll
        for (int it = 0; it < 4; ++it) asm volatile("" : "+v"(bfrag[g][it]));
#pragma unroll
        for (int it = 0; it < 2; ++it) asm volatile("" : "+v"(bx[g][it]));
    }

    int bl = tid >> 4, ul = tid & 15;
    int be = bbase + bl, ue = u0 + ul;
    float brr = bhh[ue], bzz = bhh[HID + ue], bnn = bhh[2 * HID + ue];
    float bihr = bih[ue], bihz = bih[HID + ue], bihn = bih[2 * HID + ue];
    unsigned short h16r = __hip_atomic_load(
        &hbp[(size_t)(gru)*BATCH * HID + (size_t)be * HID + ue],
        __ATOMIC_RELAXED, __HIP_MEMORY_SCOPE_AGENT);

    const int* seqr0 = seq + (size_t)(bbase + m) * LPRE;
    const int* seqr1 = seq + (size_t)(bbase + 16 + m) * LPRE;

    // ---- prologue: compute xsh[0] for t=0
    {
        int ta = seqr0[0], tb = seqr1[0];
        const unsigned short* ea = embb + (size_t)ta * EMBD + ks * 64 + q * 8;
        const unsigned short* eb = embb + (size_t)tb * EMBD + ks * 64 + q * 8;
        bf16x8 a00 = *(const bf16x8*)ea, a01 = *(const bf16x8*)(ea + 32);
        bf16x8 a10 = *(const bf16x8*)eb, a11 = *(const bf16x8*)(eb + 32);
        f32x4 ax[2][3] = {};
#pragma unroll
        for (int g = 0; g < 3; ++g) {
            ax[0][g] = __builtin_amdgcn_mfma_f32_16x16x32_bf16(a00, bx[g][0], ax[0][g], 0, 0, 0);
            ax[0][g] = __builtin_amdgcn_mfma_f32_16x16x32_bf16(a01, bx[g][1], ax[0][g], 0, 0, 0);
            ax[1][g] = __builtin_amdgcn_mfma_f32_16x16x32_bf16(a10, bx[g][0], ax[1][g], 0, 0, 0);
            ax[1][g] = __builtin_amdgcn_mfma_f32_16x16x32_bf16(a11, bx[g][1], ax[1][g], 0, 0, 0);
        }
#pragma unroll
        for (int g = 0; g < 3; ++g)
#pragma unroll
            for (int reg = 0; reg < 4; ++reg) {
                gl[ks][q * 4 + reg][g][m] = ax[0][g][reg];
                gl[ks][16 + q * 4 + reg][g][m] = ax[1][g][reg];
            }
        __syncthreads();
        float s0 = 0.f, s1 = 0.f, s2 = 0.f;
#pragma unroll
        for (int k2 = 0; k2 < 8; ++k2) {
            s0 += gl[k2][bl][0][ul];
            s1 += gl[k2][bl][1][ul];
            s2 += gl[k2][bl][2][ul];
        }
        xsh[0][bl][0][ul] = f2bf(s0 + bihr);
        xsh[0][bl][1][ul] = f2bf(s1 + bihz);
        xsh[0][bl][2][ul] = f2bf(s2 + bihn);
        __syncthreads();
    }

    for (int tl = 0; tl < LPRE; ++tl) {
        int p = tl & 1;
        const unsigned short* hb = hbp + ((size_t)p * 2 + gru) * BATCH * HID;
        unsigned short* hob = hbp + ((size_t)(p ^ 1) * 2 + gru) * BATCH * HID;
        bool more = (tl < LPRE - 1);

        // coherent h loads
        const unsigned short* pa0 = hb + (size_t)(bbase + m) * HID + ks * 128 + q * 8;
        const unsigned short* pa1 = pa0 + (size_t)16 * HID;
        u32x4 av0[4], av1[4];
#pragma unroll
        for (int it = 0; it < 4; ++it) {
            asm volatile("global_load_dwordx4 %0, %1, off sc0 sc1"
                         : "=v"(av0[it]) : "v"(pa0 + it * 32));
            asm volatile("global_load_dwordx4 %0, %1, off sc0 sc1"
                         : "=v"(av1[it]) : "v"(pa1 + it * 32));
        }
        asm volatile("s_waitcnt vmcnt(0)" ::: "memory");
        __builtin_amdgcn_sched_barrier(0);

        f32x4 acc[3][2] = {};
#pragma unroll
        for (int it = 0; it < 4; ++it)
#pragma unroll
            for (int g = 0; g < 3; ++g) {
                acc[g][0] = __builtin_amdgcn_mfma_f32_16x16x32_bf16(*(bf16x8*)&av0[it], bfrag[g][it], acc[g][0], 0, 0, 0);
                acc[g][1] = __builtin_amdgcn_mfma_f32_16x16x32_bf16(*(bf16x8*)&av1[it], bfrag[g][it], acc[g][1], 0, 0, 0);
            }
#pragma unroll
        for (int g = 0; g < 3; ++g)
#pragma unroll
            for (int reg = 0; reg < 4; ++reg) {
                gl[ks][q * 4 + reg][g][m] = acc[g][0][reg];
                gl[ks][16 + q * 4 + reg][g][m] = acc[g][1][reg];
            }
        // issue emb loads for t+1 (plain cached loads; compiler inserts waits)
        bf16x8 a00, a01, a10, a11;
        if (more) {
            int ta = seqr0[tl + 1], tb = seqr1[tl + 1];
            const unsigned short* ea = embb + (size_t)ta * EMBD + ks * 64 + q * 8;
            const unsigned short* eb = embb + (size_t)tb * EMBD + ks * 64 + q * 8;
            a00 = *(const bf16x8*)ea; a01 = *(const bf16x8*)(ea + 32);
            a10 = *(const bf16x8*)eb; a11 = *(const bf16x8*)(eb + 32);
        }
        __syncthreads();                                    // S1: gl(h) ready
        float ar = 0.f, az = 0.f, an = 0.f;
#pragma unroll
        for (int k2 = 0; k2 < 8; ++k2) {
            ar += gl[k2][bl][0][ul];
            az += gl[k2][bl][1][ul];
            an += gl[k2][bl][2][ul];
        }
        float xr = bf2f(xsh[p][bl][0][ul]);
        float xz = bf2f(xsh[p][bl][1][ul]);
        float xn = bf2f(xsh[p][bl][2][ul]);
        float r = sigmoidf_(xr + ar + brr);
        float z = sigmoidf_(xz + az + bzz);
        float n = tanhf_(xn + r * (an + bnn));
        float hnew = (1.f - z) * n + z * bf2f(h16r);
        unsigned short h16 = f2bf(hnew);
        h16r = h16;
        hsh[bl][ul] = h16;
        enc[((size_t)be * SRC + gru * LPRE + tl) * HID + ue] = h16;
        if (tl == LPRE - 1) hf[((size_t)gru * BATCH + be) * HID + ue] = hnew;
        // xw MFMA for t+1 (idle-shadow work)
        f32x4 ax[2][3] = {};
        if (more) {
#pragma unroll
            for (int g = 0; g < 3; ++g) {
                ax[0][g] = __builtin_amdgcn_mfma_f32_16x16x32_bf16(a00, bx[g][0], ax[0][g], 0, 0, 0);
                ax[0][g] = __builtin_amdgcn_mfma_f32_16x16x32_bf16(a01, bx[g][1], ax[0][g], 0, 0, 0);
                ax[1][g] = __builtin_amdgcn_mfma_f32_16x16x32_bf16(a10, bx[g][0], ax[1][g], 0, 0, 0);
                ax[1][g] = __builtin_amdgcn_mfma_f32_16x16x32_bf16(a11, bx[g][1], ax[1][g], 0, 0, 0);
            }
        }
        __syncthreads();                                    // S2: hsh ready; gl free
        if (more) {
#pragma unroll
            for (int g = 0; g < 3; ++g)
#pragma unroll
                for (int reg = 0; reg < 4; ++reg) {
                    gl[ks][q * 4 + reg][g][m] = ax[0][g][reg];
                    gl[ks][16 + q * 4 + reg][g][m] = ax[1][g][reg];
                }
        }
        if (tid < 64) {
            int row = tid >> 1, half = tid & 1;
            u32x4 hv = *(const u32x4*)&hsh[row][half * 8];
            unsigned short* dst = hob + (size_t)(bbase + row) * HID + u0 + half * 8;
            asm volatile("global_store_dwordx4 %0, %1, off sc0 sc1"
                         :: "v"(dst), "v"(hv) : "memory");
        }
        if (more) {
            __syncthreads();                                // S3: gl(xw) ready
            float s0 = 0.f, s1 = 0.f, s2 = 0.f;
#pragma unroll
            for (int k2 = 0; k2 < 8; ++k2) {
                s0 += gl[k2][bl][0][ul];
                s1 += gl[k2][bl][1][ul];
                s2 += gl[k2][bl][2][ul];
            }
            xsh[p ^ 1][bl][0][ul] = f2bf(s0 + bihr);
            xsh[p ^ 1][bl][1][ul] = f2bf(s1 + bihz);
            xsh[p ^ 1][bl][2][ul] = f2bf(s2 + bihn);
            uint32 t1 = (uint32)(tl + 1);
            if (tid < 64)
                asm volatile("s_waitcnt vmcnt(0)" ::: "memory");   // drain h stores (wave0)
            if (tid == 0)
                __hip_atomic_store(&slots[sid], t1, __ATOMIC_RELAXED, __HIP_MEMORY_SCOPE_AGENT);
            if (leader && tid < 64) {
                for (;;) {
                    uint32 s = __hip_atomic_load(&slots[tid], __ATOMIC_RELAXED, __HIP_MEMORY_SCOPE_AGENT);
                    if (__all(s >= t1)) break;
                    __builtin_amdgcn_s_sleep(1);
                }
                if (tid == 0)
                    __hip_atomic_store(gen, t1, __ATOMIC_RELAXED, __HIP_MEMORY_SCOPE_AGENT);
            }
            if (tid == 0) {
                while (__hip_atomic_load(gen, __ATOMIC_RELAXED, __HIP_MEMORY_SCOPE_AGENT) < t1)
                    __builtin_amdgcn_s_sleep(1);
            }
            __syncthreads();                                // S4
        }
    }
}

// -------- MFMA small GEMM (M=64): out[64][N] = act(A @ Wb.T + bias)
__global__ __launch_bounds__(256) void kg64(const float* __restrict__ A1, int K1,
                                            const float* __restrict__ A2, int K2,
                                            const unsigned short* __restrict__ Wb,
                                            const float* __restrict__ bias,
                                            float* __restrict__ out, int N, int act) {
    __shared__ uint4 Asl[4][64];
    int tid = threadIdx.x;
    int col0 = blockIdx.x * 64;
    int lane = tid & 63, w = tid >> 6;
    int q = lane >> 4, m = lane & 15;
    int K = K1 + K2;
    int arow = tid >> 2, akg = tid & 3;
    const unsigned short* wp = Wb + (size_t)(col0 + w * 16 + m) * K + q * 8;
    f32x4 acc[4] = {};
    for (int kk = 0; kk < K; kk += 32) {
        int k0 = kk + akg * 8;
        const float* ap = (k0 < K1) ? (A1 + (size_t)arow * K1 + k0)
                                    : (A2 + (size_t)arow * K2 + (k0 - K1));
        float4 v0 = *(const float4*)ap;
        float4 v1 = *(const float4*)(ap + 4);
        __syncthreads();
        Asl[akg][arow ^ (akg << 2)] = pack8(v0, v1);
        __syncthreads();
        bf16x8 bfv = *(const bf16x8*)(wp + kk);
        bf16x8 af[4];
#pragma unroll
        for (int i = 0; i < 4; i++) af[i] = *(bf16x8*)&Asl[q][(i * 16 + m) ^ (q << 2)];
#pragma unroll
        for (int i = 0; i < 4; i++)
            acc[i] = __builtin_amdgcn_mfma_f32_16x16x32_bf16(af[i], bfv, acc[i], 0, 0, 0);
    }
    int j = col0 + w * 16 + m;
    float bv = bias ? bias[j] : 0.f;
#pragma unroll
    for (int i = 0; i < 4; i++)
#pragma unroll
        for (int reg = 0; reg < 4; reg++) {
            int b = i * 16 + q * 4 + reg;
            float v = acc[i][reg] + bv;
            if (act == 1) v = tanhf_(v);
            out[(size_t)b * N + j] = v;
        }
}

// -------- attention energies (MFMA) + fused pointer-dot (dvec = relu(enc).fcoW[:H])
__global__ __launch_bounds__(256) void kattn(const unsigned short* __restrict__ enc,
                                             const unsigned short* __restrict__ Wb,
                                             const float* __restrict__ attn_b,
                                             const float* __restrict__ hidA,
                                             const float* __restrict__ vW,
                                             const float* __restrict__ fcoW,
                                             float* __restrict__ e,
                                             float* __restrict__ dvec) {
    __shared__ uint4 Asl[4][128];
    __shared__ uint4 Bsl[4][128];
    __shared__ float red[2][128][17];
    __shared__ float dred[128][2];
    __shared__ float fsh[HID];
    int tid = threadIdx.x;
    int row0 = blockIdx.x * 128, col0 = blockIdx.y * 128;
    bool dwork = (blockIdx.y == 0);
    if (dwork)
        for (int l = tid; l < HID; l += 256) fsh[l] = fcoW[l];
    int lane = tid & 63, w = tid >> 6;
    int wm = w >> 1, wn = w & 1;
    int q = lane >> 4, m = lane & 15;
    int r0s = tid & 127, g0s = tid >> 7;
    int g1s = g0s + 2;
    f32x4 acc[4][4] = {};
    float dacc = 0.f;
    for (int kk = 0; kk < HID; kk += 32) {
        uint4 av0 = *(const uint4*)(enc + (size_t)(row0 + r0s) * HID + kk + g0s * 8);
        uint4 av1 = *(const uint4*)(enc + (size_t)(row0 + r0s) * HID + kk + g1s * 8);
        uint4 bv0 = *(const uint4*)(Wb + (size_t)(col0 + r0s) * HID + kk + g0s * 8);
        uint4 bv1 = *(const uint4*)(Wb + (size_t)(col0 + r0s) * HID + kk + g1s * 8);
        __syncthreads();
        Asl[g0s][r0s ^ (g0s << 2)] = av0;
        Asl[g1s][r0s ^ (g1s << 2)] = av1;
        Bsl[g0s][r0s ^ (g0s << 2)] = bv0;
        Bsl[g1s][r0s ^ (g1s << 2)] = bv1;
        __syncthreads();
        bf16x8 af[4], bfv[4];
#pragma unroll
        for (int i = 0; i < 4; i++) af[i] = *(bf16x8*)&Asl[q][(wm * 64 + i * 16 + m) ^ (q << 2)];
#pragma unroll
        for (int j = 0; j < 4; j++) bfv[j] = *(bf16x8*)&Bsl[q][(wn * 64 + j * 16 + m) ^ (q << 2)];
        if (dwork) {
            int r2 = tid >> 1, sp = tid & 1;
#pragma unroll
            for (int sg = 0; sg < 2; sg++) {
                int seg = sp * 2 + sg;
                uint4 v = Asl[seg][r2 ^ (seg << 2)];
                const uint32* vw = (const uint32*)&v;
#pragma unroll
                for (int wd = 0; wd < 4; wd++) {
                    float e0, e1;
                    up2(vw[wd], e0, e1);
                    int kb = kk + seg * 8 + wd * 2;
                    dacc += fmaxf(e0, 0.f) * fsh[kb] + fmaxf(e1, 0.f) * fsh[kb + 1];
                }
            }
        }
#pragma unroll
        for (int i = 0; i < 4; i++)
#pragma unroll
            for (int j = 0; j < 4; j++)
                acc[i][j] = __builtin_amdgcn_mfma_f32_16x16x32_bf16(af[i], bfv[j], acc[i][j], 0, 0, 0);
    }
    int b = row0 / SRC;
#pragma unroll
    for (int i = 0; i < 4; i++)
#pragma unroll
        for (int reg = 0; reg < 4; reg++) {
            int row_local = wm * 64 + i * 16 + q * 4 + reg;
            float s = 0.f;
#pragma unroll
            for (int j = 0; j < 4; j++) {
                int col = col0 + wn * 64 + j * 16 + m;
                float v = acc[i][j][reg] + hidA[(size_t)b * HID + col] + attn_b[col];
                s += vW[col] * tanhf(v);
            }
            red[wn][row_local][m] = s;
        }
    if (dwork) dred[tid >> 1][tid & 1] = dacc;
    __syncthreads();
    if (tid < 128) {
        float s = 0.f;
        for (int c = 0; c < 16; c++) s += red[0][tid][c] + red[1][tid][c];
        atomicAdd(e + row0 + tid, s);
        if (dwork) dvec[row0 + tid] = dred[tid][0] + dred[tid][1];
    }
}

// -------- fused softmax + weighted sum
__global__ __launch_bounds__(256) void kswW(const float* __restrict__ evec,
                                            const unsigned short* __restrict__ enc,
                                            float* __restrict__ wout) {
    __shared__ float red[256];
    __shared__ float asw[512];
    int b = blockIdx.y;
    int tid = threadIdx.x;
    float v0 = evec[(size_t)b * SRC + tid], v1 = evec[(size_t)b * SRC + 256 + tid];
    red[tid] = fmaxf(v0, v1);
    __syncthreads();
    for (int st = 128; st > 0; st >>= 1) {
        if (tid < st) red[tid] = fmaxf(red[tid], red[tid + st]);
        __syncthreads();
    }
    float mx = red[0];
    __syncthreads();
    float e0 = __expf(v0 - mx), e1 = __expf(v1 - mx);
    red[tid] = e0 + e1;
    __syncthreads();
    for (int st = 128; st > 0; st >>= 1) {
        if (tid < st) red[tid] += red[tid + st];
        __syncthreads();
    }
    float inv = 1.0f / red[0];
    asw[tid] = e0 * inv;
    asw[tid + 256] = e1 * inv;
    __syncthreads();
    int h = blockIdx.x * 256 + tid;
    float acc = 0.f;
    for (int s = 0; s < SRC; s++) acc += asw[s] * bf2f(enc[((size_t)b * SRC + s) * HID + h]);
    wout[(size_t)b * HID + h] = acc;
}

__global__ __launch_bounds__(256) void koc(const float* __restrict__ o2,
                                           const float* __restrict__ fcoW,
                                           float* __restrict__ oc) {
    int b = blockIdx.x;
    int tid = threadIdx.x;
    __shared__ float red[256];
    float s = 0.f;
    for (int j = tid; j < HID; j += 256) s += fmaxf(o2[(size_t)b * HID + j], 0.f) * fcoW[HID + j];
    red[tid] = s;
    __syncthreads();
    for (int st = 128; st > 0; st >>= 1) {
        if (tid < st) red[tid] += red[tid + st];
        __syncthreads();
    }
    if (tid == 0) oc[b] = red[0];
}

__global__ __launch_bounds__(256) void kout(const float* __restrict__ dvec,
                                            const float* __restrict__ oc,
                                            const float* __restrict__ fcob,
                                            float* __restrict__ out) {
    int idx = blockIdx.x * 256 + threadIdx.x;
    int b = idx >> 9, s = idx & 511;
    float logit = dvec[idx] + oc[b] + fcob[0];
    float sig = frcp_(1.f + __expf(-fminf(fmaxf(logit, -30.f), 30.f)));
    size_t base = (s < LPRE) ? ((size_t)b * 4096 + s)
                             : (262144 + (size_t)b * 4096 + (s - 256));
    for (int l = 0; l < 16; l++) out[base + (size_t)l * 256] = sig;
}

extern "C" void kernel_launch(void* const* d_in, const int* in_sizes, int n_in,
                              void* d_out, int out_size, void* d_ws, size_t ws_size,
                              hipStream_t stream) {
    (void)in_sizes; (void)n_in; (void)out_size; (void)ws_size;
    const int* pre_seq = (const int*)d_in[0];
    const int* post_seq = (const int*)d_in[1];
    const float* emb = (const float*)d_in[3];
    const float* Wih_pre = (const float*)d_in[4];
    const float* Whh_pre = (const float*)d_in[5];
    const float* bih_pre = (const float*)d_in[6];
    const float* bhh_pre = (const float*)d_in[7];
    const float* Wih_post = (const float*)d_in[8];
    const float* Whh_post = (const float*)d_in[9];
    const float* bih_post = (const float*)d_in[10];
    const float* bhh_post = (const float*)d_in[11];
    const float* fc_W = (const float*)d_in[12];
    const float* fc_b = (const float*)d_in[13];
    const float* attn_W = (const float*)d_in[14];
    const float* attn_b = (const float*)d_in[15];
    const float* v_W = (const float*)d_in[16];
    const float* fc1_W = (const float*)d_in[17];
    const float* fc1_b = (const float*)d_in[18];
    const float* fc2_W = (const float*)d_in[19];
    const float* fc2_b = (const float*)d_in[20];
    const float* fco_W = (const float*)d_in[21];
    const float* fco_b = (const float*)d_in[22];
    float* out = (float*)d_out;

    // workspace (~137 MB; no xw buffer)
    char* ws = (char*)d_ws;
    unsigned short* enc = (unsigned short*)ws;    ws += (size_t)BATCH * SRC * HID * 2;       // 67.1 MB
    unsigned short* hbp = (unsigned short*)ws;    ws += (size_t)2 * 2 * BATCH * HID * 2;     // 0.5 MB
    float* hf = (float*)ws;                       ws += (size_t)2 * BATCH * HID * 4;         // 0.5 MB
    unsigned short* embb = (unsigned short*)ws;   ws += (size_t)VOCAB * EMBD * 2;            // 32.8 MB
    unsigned short* Wihb = (unsigned short*)ws;   ws += (size_t)2 * G3 * EMBD * 2;           // 6.3 MB
    unsigned short* Whhb = (unsigned short*)ws;   ws += (size_t)2 * G3 * HID * 2;            // 12.6 MB
    unsigned short* attnWb = (unsigned short*)ws; ws += (size_t)HID * HID * 2;               // 2.1 MB
    unsigned short* attnWa = (unsigned short*)ws; ws += (size_t)HID * HID * 2;               // 2.1 MB
    unsigned short* fcWb = (unsigned short*)ws;   ws += (size_t)HID * 2 * HID * 2;           // 4.2 MB
    unsigned short* fc1b = (unsigned short*)ws;   ws += (size_t)HID * HID * 2;               // 2.1 MB
    unsigned short* fc2b = (unsigned short*)ws;   ws += (size_t)HID * 2 * HID * 2;           // 4.2 MB
    uint32* bar = (uint32*)ws;                    ws += 4096;
    float* dvec = (float*)ws;                     ws += (size_t)BATCH * SRC * 4;
    float* hidden = (float*)ws;                   ws += (size_t)BATCH * HID * 4;
    float* hidA = (float*)ws;                     ws += (size_t)BATCH * HID * 4;
    float* evec = (float*)ws;                     ws += (size_t)BATCH * SRC * 4;
    float* wsum = (float*)ws;                     ws += (size_t)BATCH * HID * 4;
    float* o1 = (float*)ws;                       ws += (size_t)BATCH * HID * 4;
    float* o2 = (float*)ws;                       ws += (size_t)BATCH * HID * 4;
    float* oc = (float*)ws;                       ws += (size_t)BATCH * 4;

    // per-call init
    hipMemsetAsync(hbp, 0, (size_t)2 * 2 * BATCH * HID * 2, stream);
    hipMemsetAsync(evec, 0, (size_t)BATCH * SRC * 4, stream);
    hipMemsetAsync(bar, 0, 4096, stream);

    // fused emb+weight pre-conversion to bf16 (one launch, 10 segments)
    {
        CvtArgs a;
        uint32 cum = 0;
        int k = 0;
        auto add = [&](const float* src, unsigned short* dst, int ld, int off, int colshift, uint32 ngrp) {
            cum += ngrp;
            a.s[k].src = src; a.s[k].dst = dst; a.s[k].ld = ld; a.s[k].off = off;
            a.s[k].colshift = colshift; a.s[k].gend = cum; k++;
        };
        add(emb, embb, EMBD, 0, 9, (uint32)(VOCAB * EMBD / 4));
        add(Wih_pre, Wihb, EMBD, 0, 9, G3 * EMBD / 4);
        add(Wih_post, Wihb + (size_t)G3 * EMBD, EMBD, 0, 9, G3 * EMBD / 4);
        add(Whh_pre, Whhb, HID, 0, 10, G3 * HID / 4);
        add(Whh_post, Whhb + (size_t)G3 * HID, HID, 0, 10, G3 * HID / 4);
        add(attn_W, attnWb, 2 * HID, HID, 10, HID * HID / 4);
        add(attn_W, attnWa, 2 * HID, 0, 10, HID * HID / 4);
        add(fc1_W, fc1b, HID, 0, 10, HID * HID / 4);
        add(fc_W, fcWb, 2 * HID, 0, 11, HID * 2 * HID / 4);
        add(fc2_W, fc2b, 2 * HID, 0, 11, HID * 2 * HID / 4);
        a.total = cum;
        kcvtN<<<2048, 256, 0, stream>>>(a);
    }

    // single persistent recurrence launch: all 256 steps, projection fused
    kstepP<<<dim3(64, 2, 2), 512, 0, stream>>>(hbp, hf, Whhb, Wihb, embb,
                                               pre_seq, post_seq,
                                               bhh_pre, bhh_post, bih_pre, bih_post,
                                               enc, bar);
    float* pre_h = hf;
    float* post_h = hf + (size_t)BATCH * HID;

    // decoder tail
    kg64<<<HID / 64, 256, 0, stream>>>(pre_h, HID, post_h, HID, fcWb, fc_b, hidden, HID, 1);
    kg64<<<HID / 64, 256, 0, stream>>>(hidden, HID, (const float*)nullptr, 0, attnWa,
                                       (const float*)nullptr, hidA, HID, 0);
    kattn<<<dim3(BATCH * SRC / 128, HID / 128), 256, 0, stream>>>(enc, attnWb, attn_b, hidA,
                                                                  v_W, fco_W, evec, dvec);
    kswW<<<dim3(HID / 256, BATCH), 256, 0, stream>>>(evec, enc, wsum);
    kg64<<<HID / 64, 256, 0, stream>>>(hidden, HID, (const float*)nullptr, 0, fc1b, fc1_b, o1, HID, 1);
    kg64<<<HID / 64, 256, 0, stream>>>(o1, HID, wsum, HID, fc2b, fc2_b, o2, HID, 1);
    koc<<<BATCH, 256, 0, stream>>>(o2, fco_W, oc);
    kout<<<BATCH * SRC / 256, 256, 0, stream>>>(dvec, oc, fco_b, out);
}

// Round 19
// 1870.809 us; speedup vs baseline: 1.0332x; 1.0332x over previous
//
#include <hip/hip_runtime.h>
#include <math.h>

#define BATCH 64
#define LPRE 256
#define EMBD 512
#define HID 1024
#define G3 3072
#define SRC 512
#define VOCAB 32000

typedef unsigned int uint32;
typedef unsigned long long u64;
typedef short bf16x8 __attribute__((ext_vector_type(8)));
typedef float f32x4 __attribute__((ext_vector_type(4)));
typedef uint32 u32x4 __attribute__((ext_vector_type(4)));

__device__ __forceinline__ float frcp_(float x) { return __builtin_amdgcn_rcpf(x); }
__device__ __forceinline__ float sigmoidf_(float x) {
    x = fminf(fmaxf(x, -30.f), 30.f);
    return frcp_(1.0f + __expf(-x));
}
__device__ __forceinline__ float tanhf_(float x) {
    x = fminf(fmaxf(x, -15.f), 15.f);
    float e = __expf(2.f * x);
    return (e - 1.f) * frcp_(e + 1.f);
}

__device__ __forceinline__ unsigned short f2bf(float f) {
    uint32 u = __float_as_uint(f);
    return (unsigned short)((u + 0x7fffu + ((u >> 16) & 1u)) >> 16);
}
__device__ __forceinline__ float bf2f(unsigned short s) { return __uint_as_float(((uint32)s) << 16); }
__device__ __forceinline__ uint4 pack8(float4 a, float4 b) {
    uint4 w;
    w.x = (uint32)f2bf(a.x) | ((uint32)f2bf(a.y) << 16);
    w.y = (uint32)f2bf(a.z) | ((uint32)f2bf(a.w) << 16);
    w.z = (uint32)f2bf(b.x) | ((uint32)f2bf(b.y) << 16);
    w.w = (uint32)f2bf(b.z) | ((uint32)f2bf(b.w) << 16);
    return w;
}
__device__ __forceinline__ void up2(uint32 u, float& f0, float& f1) {
    f0 = __uint_as_float(u << 16);
    f1 = __uint_as_float(u & 0xffff0000u);
}

// -------- fused fp32->bf16 conversion: up to 10 strided segments, one launch.
struct CvtSeg { const float* src; unsigned short* dst; int ld, off, colshift; uint32 gend; };
struct CvtArgs { CvtSeg s[10]; uint32 total; };

__global__ __launch_bounds__(256) void kcvtN(CvtArgs a) {
    uint32 stride = gridDim.x * 256;
    for (uint32 g = blockIdx.x * 256 + threadIdx.x; g < a.total; g += stride) {
        uint32 gs = 0;
#pragma unroll
        for (int k = 0; k < 10; k++) {
            if (g < a.s[k].gend) {
                uint32 lg = g - gs;
                size_t e = (size_t)lg * 4;
                int r = (int)(e >> a.s[k].colshift);
                int c = (int)(e & (((size_t)1 << a.s[k].colshift) - 1));
                const float* sp = a.s[k].src + (size_t)r * a.s[k].ld + a.s[k].off + c;
                float4 v = *(const float4*)sp;
                uint2 w;
                w.x = (uint32)f2bf(v.x) | ((uint32)f2bf(v.y) << 16);
                w.y = (uint32)f2bf(v.z) | ((uint32)f2bf(v.w) << 16);
                *(uint2*)(a.s[k].dst + e) = w;
                break;
            }
            gs = a.s[k].gend;
        }
    }
}

// -------- MFMA projection, both GRUs via blockIdx.z. 128x128 tiles.
// embb (bf16 emb) used when non-null; else fp32 emb + in-kernel pack (identical rounding).
__global__ __launch_bounds__(256) void kproj(const int* __restrict__ pre_seq,
                                             const int* __restrict__ post_seq, int t0,
                                             const float* __restrict__ emb,
                                             const unsigned short* __restrict__ embb,
                                             const unsigned short* __restrict__ Wihb,
                                             const float* __restrict__ bih_pre,
                                             const float* __restrict__ bih_post,
                                             unsigned short* __restrict__ xw, int chunk) {
    __shared__ uint4 Asl[4][128];
    __shared__ uint4 Bsl[4][128];
    __shared__ int tok[128];
    int gru = blockIdx.z;
    const int* seq = gru ? post_seq : pre_seq;
    const unsigned short* Wb = Wihb + (size_t)gru * G3 * EMBD;
    const float* bih = gru ? bih_post : bih_pre;
    unsigned short* xwout = xw + (size_t)gru * BATCH * chunk * G3;
    int tid = threadIdx.x;
    int row0 = blockIdx.x * 128, col0 = blockIdx.y * 128;
    if (tid < 128) {
        int rr = row0 + tid;
        tok[tid] = seq[(rr / chunk) * LPRE + t0 + (rr % chunk)];
    }
    __syncthreads();
    int lane = tid & 63, w = tid >> 6;
    int wm = w >> 1, wn = w & 1;
    int q = lane >> 4, m = lane & 15;
    int r0s = tid & 127, g0s = tid >> 7;
    int g1s = g0s + 2;
    f32x4 acc[4][4] = {};
    for (int kk = 0; kk < EMBD; kk += 32) {
        uint4 apack0, apack1;
        if (embb) {
            apack0 = *(const uint4*)(embb + (size_t)tok[r0s] * EMBD + kk + g0s * 8);
            apack1 = *(const uint4*)(embb + (size_t)tok[r0s] * EMBD + kk + g1s * 8);
        } else {
            const float* a0p = emb + (size_t)tok[r0s] * EMBD + kk + g0s * 8;
            const float* a1p = emb + (size_t)tok[r0s] * EMBD + kk + g1s * 8;
            float4 av00 = *(const float4*)a0p, av01 = *(const float4*)(a0p + 4);
            float4 av10 = *(const float4*)a1p, av11 = *(const float4*)(a1p + 4);
            apack0 = pack8(av00, av01);
            apack1 = pack8(av10, av11);
        }
        uint4 bv0 = *(const uint4*)(Wb + (size_t)(col0 + r0s) * EMBD + kk + g0s * 8);
        uint4 bv1 = *(const uint4*)(Wb + (size_t)(col0 + r0s) * EMBD + kk + g1s * 8);
        __syncthreads();
        Asl[g0s][r0s ^ (g0s << 2)] = apack0;
        Asl[g1s][r0s ^ (g1s << 2)] = apack1;
        Bsl[g0s][r0s ^ (g0s << 2)] = bv0;
        Bsl[g1s][r0s ^ (g1s << 2)] = bv1;
        __syncthreads();
        bf16x8 af[4], bfv[4];
#pragma unroll
        for (int i = 0; i < 4; i++) af[i] = *(bf16x8*)&Asl[q][(wm * 64 + i * 16 + m) ^ (q << 2)];
#pragma unroll
        for (int j = 0; j < 4; j++) bfv[j] = *(bf16x8*)&Bsl[q][(wn * 64 + j * 16 + m) ^ (q << 2)];
#pragma unroll
        for (int i = 0; i < 4; i++)
#pragma unroll
            for (int j = 0; j < 4; j++)
                acc[i][j] = __builtin_amdgcn_mfma_f32_16x16x32_bf16(af[i], bfv[j], acc[i][j], 0, 0, 0);
    }
#pragma unroll
    for (int i = 0; i < 4; i++)
#pragma unroll
        for (int j = 0; j < 4; j++)
#pragma unroll
            for (int reg = 0; reg < 4; reg++) {
                int row = row0 + wm * 64 + i * 16 + q * 4 + reg;
                int col = col0 + wn * 64 + j * 16 + m;
                xwout[(size_t)row * G3 + col] = f2bf(acc[i][j][reg] + bih[col]);
            }
}

// -------- persistent GRU recurrence: `chunk` steps per launch.  [Proven 1.873ms
// configuration: leader+gen 4-domain barrier, wide coherent h I/O.]
__global__ __launch_bounds__(512, 2) void kstepP(unsigned short* __restrict__ hbp,
                                                 float* __restrict__ hf,
                                                 const unsigned short* __restrict__ Whhb,
                                                 const float* __restrict__ bhh0,
                                                 const float* __restrict__ bhh1,
                                                 const unsigned short* __restrict__ xw,
                                                 unsigned short* __restrict__ enc,
                                                 uint32* __restrict__ bar,
                                                 int t0, int chunk) {
    __shared__ float gl[8][32][3][17];      // 52 KB: per-K-slice gate partials
    __shared__ unsigned short hsh[32][16];  // 1 KB: h gather for wide stores
    int gru = blockIdx.z;
    int mh = blockIdx.y;
    int u0 = blockIdx.x * 16;
    int tid = threadIdx.x;
    int ks = tid >> 6;                    // 0..7 K-slice
    int lane = tid & 63;
    int q = lane >> 4, m = lane & 15;
    int bbase = mh * 32;
    const unsigned short* Wg = Whhb + (size_t)gru * G3 * HID;
    const float* bhh = gru ? bhh1 : bhh0;

    int dom = gru * 2 + mh;
    uint32* slots = bar + (size_t)dom * 128;       // 4 domains, 512B apart
    uint32* gen = bar + 512 + (size_t)dom * 32;
    int sid = blockIdx.x;                          // 0..63 within domain
    bool leader = (blockIdx.x == 0);

    bf16x8 bfrag[3][4];
#pragma unroll
    for (int g = 0; g < 3; ++g) {
        const unsigned short* pb = Wg + (size_t)(g * HID + u0 + m) * HID + ks * 128 + q * 8;
#pragma unroll
        for (int it = 0; it < 4; ++it) bfrag[g][it] = *(const bf16x8*)(pb + it * 32);
    }
#pragma unroll
    for (int g = 0; g < 3; ++g)
#pragma unroll
        for (int it = 0; it < 4; ++it) asm volatile("" : "+v"(bfrag[g][it]));

    int bl = tid >> 4, ul = tid & 15;
    int be = bbase + bl, ue = u0 + ul;
    float brr = bhh[ue], bzz = bhh[HID + ue], bnn = bhh[2 * HID + ue];
    unsigned short h16r = __hip_atomic_load(
        &hbp[(size_t)(((t0 & 1) * 2 + gru) * BATCH + be) * HID + ue],
        __ATOMIC_RELAXED, __HIP_MEMORY_SCOPE_AGENT);

    const unsigned short* xwb = xw + ((size_t)(gru * BATCH + be) * chunk) * G3;
    float xr = bf2f(xwb[ue]);
    float xz = bf2f(xwb[HID + ue]);
    float xn = bf2f(xwb[2 * HID + ue]);

    for (int tl = 0; tl < chunk; ++tl) {
        int t = t0 + tl;
        int p = t & 1;
        const unsigned short* hb = hbp + ((size_t)p * 2 + gru) * BATCH * HID;
        unsigned short* hob = hbp + ((size_t)(p ^ 1) * 2 + gru) * BATCH * HID;

        const unsigned short* pa0 = hb + (size_t)(bbase + m) * HID + ks * 128 + q * 8;
        const unsigned short* pa1 = pa0 + (size_t)16 * HID;
        u32x4 av0[4], av1[4];
#pragma unroll
        for (int it = 0; it < 4; ++it) {
            asm volatile("global_load_dwordx4 %0, %1, off sc0 sc1"
                         : "=v"(av0[it]) : "v"(pa0 + it * 32));
            asm volatile("global_load_dwordx4 %0, %1, off sc0 sc1"
                         : "=v"(av1[it]) : "v"(pa1 + it * 32));
        }
        asm volatile("s_waitcnt vmcnt(0)" ::: "memory");
        __builtin_amdgcn_sched_barrier(0);

        f32x4 acc[3][2] = {};
#pragma unroll
        for (int it = 0; it < 4; ++it)
#pragma unroll
            for (int g = 0; g < 3; ++g) {
                acc[g][0] = __builtin_amdgcn_mfma_f32_16x16x32_bf16(*(bf16x8*)&av0[it], bfrag[g][it], acc[g][0], 0, 0, 0);
                acc[g][1] = __builtin_amdgcn_mfma_f32_16x16x32_bf16(*(bf16x8*)&av1[it], bfrag[g][it], acc[g][1], 0, 0, 0);
            }
#pragma unroll
        for (int g = 0; g < 3; ++g)
#pragma unroll
            for (int reg = 0; reg < 4; ++reg) {
                gl[ks][q * 4 + reg][g][m] = acc[g][0][reg];
                gl[ks][16 + q * 4 + reg][g][m] = acc[g][1][reg];
            }
        __syncthreads();
        float ar = 0.f, az = 0.f, an = 0.f;
#pragma unroll
        for (int k2 = 0; k2 < 8; ++k2) {
            ar += gl[k2][bl][0][ul];
            az += gl[k2][bl][1][ul];
            an += gl[k2][bl][2][ul];
        }
        float r = sigmoidf_(xr + ar + brr);
        float z = sigmoidf_(xz + az + bzz);
        float n = tanhf_(xn + r * (an + bnn));
        float hnew = (1.f - z) * n + z * bf2f(h16r);
        unsigned short h16 = f2bf(hnew);
        h16r = h16;
        hsh[bl][ul] = h16;
        enc[((size_t)be * SRC + gru * LPRE + t) * HID + ue] = h16;
        if (t == LPRE - 1) hf[((size_t)gru * BATCH + be) * HID + ue] = hnew;
        __syncthreads();
        if (tid < 64) {
            int row = tid >> 1, half = tid & 1;
            u32x4 hv = *(const u32x4*)&hsh[row][half * 8];
            unsigned short* dst = hob + (size_t)(bbase + row) * HID + u0 + half * 8;
            asm volatile("global_store_dwordx4 %0, %1, off sc0 sc1"
                         :: "v"(dst), "v"(hv) : "memory");
        }
        if (tl < chunk - 1) {
            uint32 t1 = (uint32)(t + 1);
            if (tid < 64)
                asm volatile("s_waitcnt vmcnt(0)" ::: "memory");
            if (tid == 0)
                __hip_atomic_store(&slots[sid], t1, __ATOMIC_RELAXED, __HIP_MEMORY_SCOPE_AGENT);
            const unsigned short* xwn = xwb + (size_t)(tl + 1) * G3;
            xr = bf2f(xwn[ue]);
            xz = bf2f(xwn[HID + ue]);
            xn = bf2f(xwn[2 * HID + ue]);
            if (leader && tid < 64) {
                for (;;) {
                    uint32 s0 = __hip_atomic_load(&slots[tid], __ATOMIC_RELAXED, __HIP_MEMORY_SCOPE_AGENT);
                    if (__all(s0 >= t1)) break;
                    __builtin_amdgcn_s_sleep(1);
                }
                if (tid == 0)
                    __hip_atomic_store(gen, t1, __ATOMIC_RELAXED, __HIP_MEMORY_SCOPE_AGENT);
            }
            if (tid == 0) {
                while (__hip_atomic_load(gen, __ATOMIC_RELAXED, __HIP_MEMORY_SCOPE_AGENT) < t1)
                    __builtin_amdgcn_s_sleep(1);
            }
            __syncthreads();
        }
    }
}

// -------- MFMA small GEMM (M=64): out[64][N] = act(A @ Wb.T + bias)
__global__ __launch_bounds__(256) void kg64(const float* __restrict__ A1, int K1,
                                            const float* __restrict__ A2, int K2,
                                            const unsigned short* __restrict__ Wb,
                                            const float* __restrict__ bias,
                                            float* __restrict__ out, int N, int act) {
    __shared__ uint4 Asl[4][64];
    int tid = threadIdx.x;
    int col0 = blockIdx.x * 64;
    int lane = tid & 63, w = tid >> 6;
    int q = lane >> 4, m = lane & 15;
    int K = K1 + K2;
    int arow = tid >> 2, akg = tid & 3;
    const unsigned short* wp = Wb + (size_t)(col0 + w * 16 + m) * K + q * 8;
    f32x4 acc[4] = {};
    for (int kk = 0; kk < K; kk += 32) {
        int k0 = kk + akg * 8;
        const float* ap = (k0 < K1) ? (A1 + (size_t)arow * K1 + k0)
                                    : (A2 + (size_t)arow * K2 + (k0 - K1));
        float4 v0 = *(const float4*)ap;
        float4 v1 = *(const float4*)(ap + 4);
        __syncthreads();
        Asl[akg][arow ^ (akg << 2)] = pack8(v0, v1);
        __syncthreads();
        bf16x8 bfv = *(const bf16x8*)(wp + kk);
        bf16x8 af[4];
#pragma unroll
        for (int i = 0; i < 4; i++) af[i] = *(bf16x8*)&Asl[q][(i * 16 + m) ^ (q << 2)];
#pragma unroll
        for (int i = 0; i < 4; i++)
            acc[i] = __builtin_amdgcn_mfma_f32_16x16x32_bf16(af[i], bfv, acc[i], 0, 0, 0);
    }
    int j = col0 + w * 16 + m;
    float bv = bias ? bias[j] : 0.f;
#pragma unroll
    for (int i = 0; i < 4; i++)
#pragma unroll
        for (int reg = 0; reg < 4; reg++) {
            int b = i * 16 + q * 4 + reg;
            float v = acc[i][reg] + bv;
            if (act == 1) v = tanhf_(v);
            out[(size_t)b * N + j] = v;
        }
}

// -------- attention energies (MFMA) + fused pointer-dot (dvec = relu(enc).fcoW[:H])
__global__ __launch_bounds__(256) void kattn(const unsigned short* __restrict__ enc,
                                             const unsigned short* __restrict__ Wb,
                                             const float* __restrict__ attn_b,
                                             const float* __restrict__ hidA,
                                             const float* __restrict__ vW,
                                             const float* __restrict__ fcoW,
                                             float* __restrict__ e,
                                             float* __restrict__ dvec) {
    __shared__ uint4 Asl[4][128];
    __shared__ uint4 Bsl[4][128];
    __shared__ float red[2][128][17];
    __shared__ float dred[128][2];
    __shared__ float fsh[HID];
    int tid = threadIdx.x;
    int row0 = blockIdx.x * 128, col0 = blockIdx.y * 128;
    bool dwork = (blockIdx.y == 0);
    if (dwork)
        for (int l = tid; l < HID; l += 256) fsh[l] = fcoW[l];
    int lane = tid & 63, w = tid >> 6;
    int wm = w >> 1, wn = w & 1;
    int q = lane >> 4, m = lane & 15;
    int r0s = tid & 127, g0s = tid >> 7;
    int g1s = g0s + 2;
    f32x4 acc[4][4] = {};
    float dacc = 0.f;
    for (int kk = 0; kk < HID; kk += 32) {
        uint4 av0 = *(const uint4*)(enc + (size_t)(row0 + r0s) * HID + kk + g0s * 8);
        uint4 av1 = *(const uint4*)(enc + (size_t)(row0 + r0s) * HID + kk + g1s * 8);
        uint4 bv0 = *(const uint4*)(Wb + (size_t)(col0 + r0s) * HID + kk + g0s * 8);
        uint4 bv1 = *(const uint4*)(Wb + (size_t)(col0 + r0s) * HID + kk + g1s * 8);
        __syncthreads();
        Asl[g0s][r0s ^ (g0s << 2)] = av0;
        Asl[g1s][r0s ^ (g1s << 2)] = av1;
        Bsl[g0s][r0s ^ (g0s << 2)] = bv0;
        Bsl[g1s][r0s ^ (g1s << 2)] = bv1;
        __syncthreads();
        bf16x8 af[4], bfv[4];
#pragma unroll
        for (int i = 0; i < 4; i++) af[i] = *(bf16x8*)&Asl[q][(wm * 64 + i * 16 + m) ^ (q << 2)];
#pragma unroll
        for (int j = 0; j < 4; j++) bfv[j] = *(bf16x8*)&Bsl[q][(wn * 64 + j * 16 + m) ^ (q << 2)];
        if (dwork) {
            int r2 = tid >> 1, sp = tid & 1;
#pragma unroll
            for (int sg = 0; sg < 2; sg++) {
                int seg = sp * 2 + sg;
                uint4 v = Asl[seg][r2 ^ (seg << 2)];
                const uint32* vw = (const uint32*)&v;
#pragma unroll
                for (int wd = 0; wd < 4; wd++) {
                    float e0, e1;
                    up2(vw[wd], e0, e1);
                    int kb = kk + seg * 8 + wd * 2;
                    dacc += fmaxf(e0, 0.f) * fsh[kb] + fmaxf(e1, 0.f) * fsh[kb + 1];
                }
            }
        }
#pragma unroll
        for (int i = 0; i < 4; i++)
#pragma unroll
            for (int j = 0; j < 4; j++)
                acc[i][j] = __builtin_amdgcn_mfma_f32_16x16x32_bf16(af[i], bfv[j], acc[i][j], 0, 0, 0);
    }
    int b = row0 / SRC;
#pragma unroll
    for (int i = 0; i < 4; i++)
#pragma unroll
        for (int reg = 0; reg < 4; reg++) {
            int row_local = wm * 64 + i * 16 + q * 4 + reg;
            float s = 0.f;
#pragma unroll
            for (int j = 0; j < 4; j++) {
                int col = col0 + wn * 64 + j * 16 + m;
                float v = acc[i][j][reg] + hidA[(size_t)b * HID + col] + attn_b[col];
                s += vW[col] * tanhf(v);
            }
            red[wn][row_local][m] = s;
        }
    if (dwork) dred[tid >> 1][tid & 1] = dacc;
    __syncthreads();
    if (tid < 128) {
        float s = 0.f;
        for (int c = 0; c < 16; c++) s += red[0][tid][c] + red[1][tid][c];
        atomicAdd(e + row0 + tid, s);
        if (dwork) dvec[row0 + tid] = dred[tid][0] + dred[tid][1];
    }
}

// -------- fused softmax + weighted sum (softmax recomputed per h-chunk block)
__global__ __launch_bounds__(256) void kswW(const float* __restrict__ evec,
                                            const unsigned short* __restrict__ enc,
                                            float* __restrict__ wout) {
    __shared__ float red[256];
    __shared__ float asw[512];
    int b = blockIdx.y;
    int tid = threadIdx.x;
    float v0 = evec[(size_t)b * SRC + tid], v1 = evec[(size_t)b * SRC + 256 + tid];
    red[tid] = fmaxf(v0, v1);
    __syncthreads();
    for (int st = 128; st > 0; st >>= 1) {
        if (tid < st) red[tid] = fmaxf(red[tid], red[tid + st]);
        __syncthreads();
    }
    float mx = red[0];
    __syncthreads();
    float e0 = __expf(v0 - mx), e1 = __expf(v1 - mx);
    red[tid] = e0 + e1;
    __syncthreads();
    for (int st = 128; st > 0; st >>= 1) {
        if (tid < st) red[tid] += red[tid + st];
        __syncthreads();
    }
    float inv = 1.0f / red[0];
    asw[tid] = e0 * inv;
    asw[tid + 256] = e1 * inv;
    __syncthreads();
    int h = blockIdx.x * 256 + tid;
    float acc = 0.f;
    for (int s = 0; s < SRC; s++) acc += asw[s] * bf2f(enc[((size_t)b * SRC + s) * HID + h]);
    wout[(size_t)b * HID + h] = acc;
}

__global__ __launch_bounds__(256) void koc(const float* __restrict__ o2,
                                           const float* __restrict__ fcoW,
                                           float* __restrict__ oc) {
    int b = blockIdx.x;
    int tid = threadIdx.x;
    __shared__ float red[256];
    float s = 0.f;
    for (int j = tid; j < HID; j += 256) s += fmaxf(o2[(size_t)b * HID + j], 0.f) * fcoW[HID + j];
    red[tid] = s;
    __syncthreads();
    for (int st = 128; st > 0; st >>= 1) {
        if (tid < st) red[tid] += red[tid + st];
        __syncthreads();
    }
    if (tid == 0) oc[b] = red[0];
}

// final combine + sigmoid + 16-way broadcast
__global__ __launch_bounds__(256) void kout(const float* __restrict__ dvec,
                                            const float* __restrict__ oc,
                                            const float* __restrict__ fcob,
                                            float* __restrict__ out) {
    int idx = blockIdx.x * 256 + threadIdx.x;   // 0..32767
    int b = idx >> 9, s = idx & 511;
    float logit = dvec[idx] + oc[b] + fcob[0];
    float sig = frcp_(1.f + __expf(-fminf(fmaxf(logit, -30.f), 30.f)));
    size_t base = (s < LPRE) ? ((size_t)b * 4096 + s)
                             : (262144 + (size_t)b * 4096 + (s - 256));
    for (int l = 0; l < 16; l++) out[base + (size_t)l * 256] = sig;
}

extern "C" void kernel_launch(void* const* d_in, const int* in_sizes, int n_in,
                              void* d_out, int out_size, void* d_ws, size_t ws_size,
                              hipStream_t stream) {
    (void)in_sizes; (void)n_in; (void)out_size;
    const int* pre_seq = (const int*)d_in[0];
    const int* post_seq = (const int*)d_in[1];
    const float* emb = (const float*)d_in[3];
    const float* Wih_pre = (const float*)d_in[4];
    const float* Whh_pre = (const float*)d_in[5];
    const float* bih_pre = (const float*)d_in[6];
    const float* bhh_pre = (const float*)d_in[7];
    const float* Wih_post = (const float*)d_in[8];
    const float* Whh_post = (const float*)d_in[9];
    const float* bih_post = (const float*)d_in[10];
    const float* bhh_post = (const float*)d_in[11];
    const float* fc_W = (const float*)d_in[12];
    const float* fc_b = (const float*)d_in[13];
    const float* attn_W = (const float*)d_in[14];
    const float* attn_b = (const float*)d_in[15];
    const float* v_W = (const float*)d_in[16];
    const float* fc1_W = (const float*)d_in[17];
    const float* fc1_b = (const float*)d_in[18];
    const float* fc2_W = (const float*)d_in[19];
    const float* fc2_b = (const float*)d_in[20];
    const float* fco_W = (const float*)d_in[21];
    const float* fco_b = (const float*)d_in[22];
    float* out = (float*)d_out;

    // CHUNK selection: 64 if workspace allows (needs ~154 MB), else 32
    const size_t fixed_bytes = 103420160ull + 65536;   // everything except xw/embb (+margin)
    int CH = (ws_size >= fixed_bytes + (size_t)2 * BATCH * 64 * G3 * 2) ? 64 : 32;

    char* ws = (char*)d_ws;
    unsigned short* xw = (unsigned short*)ws;     ws += (size_t)2 * BATCH * CH * G3 * 2;     // 25.2/50.3 MB
    unsigned short* enc = (unsigned short*)ws;    ws += (size_t)BATCH * SRC * HID * 2;       // 67.1 MB
    unsigned short* hbp = (unsigned short*)ws;    ws += (size_t)2 * 2 * BATCH * HID * 2;     // 0.5 MB
    float* hf = (float*)ws;                       ws += (size_t)2 * BATCH * HID * 4;         // 0.5 MB
    unsigned short* Wihb = (unsigned short*)ws;   ws += (size_t)2 * G3 * EMBD * 2;           // 6.3 MB
    unsigned short* Whhb = (unsigned short*)ws;   ws += (size_t)2 * G3 * HID * 2;            // 12.6 MB
    unsigned short* attnWb = (unsigned short*)ws; ws += (size_t)HID * HID * 2;               // 2.1 MB
    unsigned short* attnWa = (unsigned short*)ws; ws += (size_t)HID * HID * 2;               // 2.1 MB
    unsigned short* fcWb = (unsigned short*)ws;   ws += (size_t)HID * 2 * HID * 2;           // 4.2 MB
    unsigned short* fc1b = (unsigned short*)ws;   ws += (size_t)HID * HID * 2;               // 2.1 MB
    unsigned short* fc2b = (unsigned short*)ws;   ws += (size_t)HID * 2 * HID * 2;           // 4.2 MB
    uint32* bar = (uint32*)ws;                    ws += 4096;
    float* dvec = (float*)ws;                     ws += (size_t)BATCH * SRC * 4;             // 0.13 MB
    float* hidden = (float*)ws;                   ws += (size_t)BATCH * HID * 4;
    float* hidA = (float*)ws;                     ws += (size_t)BATCH * HID * 4;
    float* evec = (float*)ws;                     ws += (size_t)BATCH * SRC * 4;
    float* avec = (float*)ws;                     ws += (size_t)BATCH * SRC * 4;             // unused (layout kept)
    float* wsum = (float*)ws;                     ws += (size_t)BATCH * HID * 4;
    float* o1 = (float*)ws;                       ws += (size_t)BATCH * HID * 4;
    float* o2 = (float*)ws;                       ws += (size_t)BATCH * HID * 4;
    float* oc = (float*)ws;                       ws += (size_t)BATCH * 4;
    (void)avec;
    // optional bf16 emb at the end of the layout
    size_t emb_bytes = (size_t)VOCAB * EMBD * 2;   // 32.8 MB
    unsigned short* embb = (unsigned short*)ws;
    int use_embb = ((size_t)((char*)(ws + 0) + emb_bytes - (char*)d_ws) <= ws_size) ? 1 : 0;

    // per-call init (harness does not re-poison between replays)
    hipMemsetAsync(hbp, 0, (size_t)2 * 2 * BATCH * HID * 2, stream);
    hipMemsetAsync(evec, 0, (size_t)BATCH * SRC * 4, stream);
    hipMemsetAsync(bar, 0, 4096, stream);

    // fused weight (+emb) pre-conversion to bf16: one launch
    {
        CvtArgs a;
        uint32 cum = 0;
        int k = 0;
        auto add = [&](const float* src, unsigned short* dst, int ld, int off, int colshift, uint32 ngrp) {
            cum += ngrp;
            a.s[k].src = src; a.s[k].dst = dst; a.s[k].ld = ld; a.s[k].off = off;
            a.s[k].colshift = colshift; a.s[k].gend = cum; k++;
        };
        if (use_embb) add(emb, embb, EMBD, 0, 9, (uint32)(VOCAB * EMBD / 4));
        add(Wih_pre, Wihb, EMBD, 0, 9, G3 * EMBD / 4);
        add(Wih_post, Wihb + (size_t)G3 * EMBD, EMBD, 0, 9, G3 * EMBD / 4);
        add(Whh_pre, Whhb, HID, 0, 10, G3 * HID / 4);
        add(Whh_post, Whhb + (size_t)G3 * HID, HID, 0, 10, G3 * HID / 4);
        add(attn_W, attnWb, 2 * HID, HID, 10, HID * HID / 4);
        add(attn_W, attnWa, 2 * HID, 0, 10, HID * HID / 4);
        add(fc1_W, fc1b, HID, 0, 10, HID * HID / 4);
        add(fc_W, fcWb, 2 * HID, 0, 11, HID * 2 * HID / 4);
        add(fc2_W, fc2b, 2 * HID, 0, 11, HID * 2 * HID / 4);
        while (k < 10) {
            a.s[k].src = Wih_pre; a.s[k].dst = Wihb; a.s[k].ld = EMBD; a.s[k].off = 0;
            a.s[k].colshift = 9; a.s[k].gend = cum; k++;
        }
        a.total = cum;
        kcvtN<<<2048, 256, 0, stream>>>(a);
    }

    // chunked projection + persistent recurrence (CH steps/launch, 4-domain barrier)
    const unsigned short* embb_arg = use_embb ? embb : (const unsigned short*)nullptr;
    for (int c = 0; c < LPRE / CH; c++) {
        kproj<<<dim3(BATCH * CH / 128, G3 / 128, 2), 256, 0, stream>>>(
            pre_seq, post_seq, c * CH, emb, embb_arg, Wihb, bih_pre, bih_post, xw, CH);
        kstepP<<<dim3(64, 2, 2), 512, 0, stream>>>(hbp, hf, Whhb, bhh_pre, bhh_post,
                                                   xw, enc, bar, c * CH, CH);
    }
    float* pre_h = hf;
    float* post_h = hf + (size_t)BATCH * HID;

    // decoder smalls via MFMA (M=64)
    kg64<<<HID / 64, 256, 0, stream>>>(pre_h, HID, post_h, HID, fcWb, fc_b, hidden, HID, 1);
    kg64<<<HID / 64, 256, 0, stream>>>(hidden, HID, (const float*)nullptr, 0, attnWa,
                                       (const float*)nullptr, hidA, HID, 0);
    kattn<<<dim3(BATCH * SRC / 128, HID / 128), 256, 0, stream>>>(enc, attnWb, attn_b, hidA,
                                                                  v_W, fco_W, evec, dvec);
    kswW<<<dim3(HID / 256, BATCH), 256, 0, stream>>>(evec, enc, wsum);
    kg64<<<HID / 64, 256, 0, stream>>>(hidden, HID, (const float*)nullptr, 0, fc1b, fc1_b, o1, HID, 1);
    kg64<<<HID / 64, 256, 0, stream>>>(o1, HID, wsum, HID, fc2b, fc2_b, o2, HID, 1);
    koc<<<BATCH, 256, 0, stream>>>(o2, fco_W, oc);
    kout<<<BATCH * SRC / 256, 256, 0, stream>>>(dvec, oc, fco_b, out);
}